// Round 5
// baseline (151.409 us; speedup 1.0000x reference)
//
#include <hip/hip_runtime.h>
#include <math.h>

// ws layout: sumF[1024] f32 | predpart[1024] f32 | cnt[16] int (byte offset 8192)
//
// Identities (verified exact, absmax 0.0 in rounds 1-4):
//  - sum(irfft2(rfft2(p)*rfft2(f))) over space = sum(p)*sum(f)   (circular conv)
//  - spatial sum of zero-padded depthwise conv = sum_w w[u,v]*RectSum + N*bias,
//    RectSum needs only plane total + <=5-wide border row/col sums (+corners).
// Single fused kernel: 1024 feat-plane blocks + 128 pred blocks; per-batch
// ticket counter (72 producers/batch) -> last block runs that batch's tail.

typedef float nfloat4 __attribute__((ext_vector_type(4)));

__device__ __forceinline__ float aload(const float* p) {
  return __hip_atomic_load(p, __ATOMIC_RELAXED, __HIP_MEMORY_SCOPE_AGENT);
}

__device__ __forceinline__ float wsum64(float v) {
  #pragma unroll
  for (int off = 32; off; off >>= 1) v += __shfl_xor(v, off, 64);
  return v;
}

__global__ __launch_bounds__(256) void k_all(
    const float* __restrict__ feat,
    const float* __restrict__ pred,
    const float* __restrict__ w_hw, const float* __restrict__ b_hw,
    const float* __restrict__ w_w,  const float* __restrict__ b_w,
    const float* __restrict__ w_h,  const float* __restrict__ b_h,
    const float* __restrict__ head,
    const float* __restrict__ dw_w, const float* __restrict__ dw_b,
    const float* __restrict__ pt_w, const float* __restrict__ pt_b,
    const float* __restrict__ ht_w, const float* __restrict__ ht_b,
    const float* __restrict__ pg_w, const float* __restrict__ pg_b,
    const float* __restrict__ hg_w, const float* __restrict__ hg_b,
    const float* __restrict__ fc_w, const float* __restrict__ fc_b,
    const float* __restrict__ pni_g, const float* __restrict__ pni_b,
    const float* __restrict__ hni_g, const float* __restrict__ hni_b,
    const float* __restrict__ pno_g, const float* __restrict__ pno_b,
    const float* __restrict__ hno_g, const float* __restrict__ hno_b,
    const float* __restrict__ fcn_g, const float* __restrict__ fcn_b,
    float* __restrict__ sumF,        // [1024]
    float* __restrict__ predpart,    // [16][8][8]
    int*   __restrict__ cnt,         // [16], pre-zeroed by memset node
    float* __restrict__ out)
{
  const int tid  = threadIdx.x;
  const int lane = tid & 63;
  const int wid  = tid >> 6;
  int b;

  if (blockIdx.x < 1024) {
    const int plane = blockIdx.x;
    b = plane >> 6;
    const int c = plane & 63;
    const nfloat4* x4 = reinterpret_cast<const nfloat4*>(feat) + (size_t)plane * 16384;

    if (c < 40) {
      // ---- identity plane: pure branch-free sum
      __shared__ float red_i[4];
      float ax = 0.f, ay = 0.f, az = 0.f, aw = 0.f;
      #pragma unroll 8
      for (int it = 0; it < 64; ++it) {
        const nfloat4 v = __builtin_nontemporal_load(&x4[it * 256 + tid]);
        ax += v.x; ay += v.y; az += v.z; aw += v.w;
      }
      float tot = (ax + ay) + (az + aw);
      #pragma unroll
      for (int off = 32; off; off >>= 1) tot += __shfl_down(tot, off, 64);
      if (lane == 0) red_i[wid] = tot;
      __syncthreads();
      if (tid == 0) sumF[plane] = (red_i[0] + red_i[1]) + (red_i[2] + red_i[3]);
    } else {
      // ---- conv plane: sum + inline border captures
      __shared__ float s_red[4];
      __shared__ float s_rs[10];        // rows 0..4 -> 0..4, rows 251..255 -> 5..9
      __shared__ float s_cs4[4][10];    // per-wave col partials, same index map
      __shared__ float s_k[4];          // corners (0,0),(0,255),(255,0),(255,255)

      float ax = 0.f, ay = 0.f, az = 0.f, aw = 0.f;
      float rowA = 0.f, rowB = 0.f, rowC = 0.f, rowD = 0.f;
      float v0x = 0.f, v0w = 0.f, v63x = 0.f, v63w = 0.f;
      #pragma unroll 8
      for (int it = 0; it < 64; ++it) {
        const nfloat4 v = __builtin_nontemporal_load(&x4[it * 256 + tid]);
        ax += v.x; ay += v.y; az += v.z; aw += v.w;
        const float s4 = (v.x + v.y) + (v.z + v.w);
        rowA += (it == 0)  ? s4 : 0.f;     // row = wid
        rowB += (it == 1)  ? s4 : 0.f;     // row = 4 + wid
        rowC += (it == 62) ? s4 : 0.f;     // row = 248 + wid
        rowD += (it == 63) ? s4 : 0.f;     // row = 252 + wid
        if (it == 0)  { v0x = v.x;  v0w = v.w; }
        if (it == 63) { v63x = v.x; v63w = v.w; }
      }
      float tot = (ax + ay) + (az + aw);
      float r0 = rowA, r1 = rowB, r2 = rowC, r3 = rowD;
      #pragma unroll
      for (int off = 32; off; off >>= 1) {
        tot += __shfl_down(tot, off, 64);
        r0  += __shfl_down(r0, off, 64);
        r1  += __shfl_down(r1, off, 64);
        r2  += __shfl_down(r2, off, 64);
        r3  += __shfl_down(r3, off, 64);
      }
      if (lane == 0) {
        s_red[wid] = tot;
        s_rs[wid] = r0;                     // rows 0..3
        if (wid == 0) s_rs[4] = r1;         // row 4
        if (wid == 3) s_rs[5] = r2;         // row 251
        s_rs[6 + wid] = r3;                 // rows 252..255
        s_cs4[wid][0] = ax; s_cs4[wid][1] = ay; s_cs4[wid][2] = az; s_cs4[wid][3] = aw;
      }
      if (lane == 1)  { s_cs4[wid][4] = ax; }                // col 4
      if (lane == 62) { s_cs4[wid][5] = aw; }                // col 251
      if (lane == 63) { s_cs4[wid][6] = ax; s_cs4[wid][7] = ay;
                        s_cs4[wid][8] = az; s_cs4[wid][9] = aw; }  // cols 252..255
      if (tid == 0)   s_k[0] = v0x;      // row 0,   col 0
      if (tid == 63)  s_k[1] = v0w;      // row 0,   col 255
      if (tid == 192) s_k[2] = v63x;     // row 255, col 0
      if (tid == 255) s_k[3] = v63w;     // row 255, col 255
      __syncthreads();

      if (tid == 0) {
        const float T = (s_red[0] + s_red[1]) + (s_red[2] + s_red[3]);
        float cs[10];
        #pragma unroll
        for (int k = 0; k < 10; ++k)
          cs[k] = (s_cs4[0][k] + s_cs4[1][k]) + (s_cs4[2][k] + s_cs4[3][k]);
        const float k00 = s_k[0], k01 = s_k[1], k10 = s_k[2], k11 = s_k[3];

        float topP[6], botP[6], leftP[6], rightP[6];
        topP[0] = botP[0] = leftP[0] = rightP[0] = 0.f;
        #pragma unroll
        for (int k = 0; k < 5; ++k) {
          topP[k+1]   = topP[k]   + s_rs[k];
          botP[k+1]   = botP[k]   + s_rs[9-k];
          leftP[k+1]  = leftP[k]  + cs[k];
          rightP[k+1] = rightP[k] + cs[9-k];
        }
        auto rect = [&](int du, int dv) -> float {
          float r = T;
          if (du > 0) r -= topP[du]; else if (du < 0) r -= botP[-du];
          if (dv > 0) r -= leftP[dv]; else if (dv < 0) r -= rightP[-dv];
          if (du > 0 && dv > 0) r += k00;
          else if (du > 0 && dv < 0) r += k01;
          else if (du < 0 && dv > 0) r += k10;
          else if (du < 0 && dv < 0) r += k11;
          return r;
        };
        float S;
        if (c < 48) {                       // 3x3 depthwise, pad (1,1)
          const int g = c - 40; const float* w = w_hw + g * 9;
          S = 65536.f * b_hw[g];
          #pragma unroll
          for (int u = 0; u < 3; ++u)
            #pragma unroll
            for (int v = 0; v < 3; ++v)
              S += w[u*3+v] * rect(u-1, v-1);
        } else if (c < 56) {                // 1x11 depthwise, pad (0,5)
          const int g = c - 48; const float* w = w_w + g * 11;
          S = 65536.f * b_w[g];
          #pragma unroll
          for (int v = 0; v < 11; ++v) S += w[v] * rect(0, v-5);
        } else {                            // 11x1 depthwise, pad (5,0)
          const int g = c - 56; const float* w = w_h + g * 11;
          S = 65536.f * b_h[g];
          #pragma unroll
          for (int u = 0; u < 11; ++u) S += w[u] * rect(u-5, 0);
        }
        sumF[plane] = S;
      }
    }
  } else {
    // ---- pred partial: block pb handles output rows [g*32, g*32+32)
    __shared__ float red[12];
    __shared__ float s_edge[3];
    const int pb = blockIdx.x - 1024;
    b = pb >> 3;
    const int g  = pb & 7;
    const int j  = tid;                 // output column 0..255
    const float* src = pred + (size_t)b * 16384;

    // jax bilinear 2x (half-pixel, edge clamp): even .25/.75, odd .75/.25
    const int kj = j >> 1;
    int c0, c1; float wc0, wc1;
    if ((j & 1) == 0) { c0 = (kj > 0) ? kj - 1 : 0; c1 = kj; wc0 = 0.25f; wc1 = 0.75f; }
    else              { c0 = kj; c1 = (kj < 127) ? kj + 1 : 127; wc0 = 0.75f; wc1 = 0.25f; }

    float accP = 0.f, accT = 0.f, accC = 0.f, redge = 0.f, cornA = 0.f, cornB = 0.f;
    const int i0 = g * 32;
    #pragma unroll 4
    for (int i = i0; i < i0 + 32; ++i) {
      const int ki = i >> 1;
      int r0, r1; float wr0, wr1;
      if ((i & 1) == 0) { r0 = (ki > 0) ? ki - 1 : 0; r1 = ki; wr0 = 0.25f; wr1 = 0.75f; }
      else              { r0 = ki; r1 = (ki < 127) ? ki + 1 : 127; wr0 = 0.75f; wr1 = 0.25f; }
      const float v = wr0 * (wc0 * src[r0*128 + c0] + wc1 * src[r0*128 + c1])
                    + wr1 * (wc0 * src[r1*128 + c0] + wc1 * src[r1*128 + c1]);
      const float p  = 1.f / (1.f + expf(-v));
      const float pm = 1.f - 1.f / (1.f + expf(-p));
      const float pa = p * pm + p;
      accP += p; accT += pa;
      if (j == 0 || j == 255) accC += pa;
      if (i == 0 || i == 255) {         // only reachable in g==0 / g==7
        redge += pa;
        if (j == 0)   cornA = pa;
        if (j == 255) cornB = pa;
      }
    }
    if (j == 255) { s_edge[0] = accC; s_edge[1] = cornB; }
    float a0 = accP, a1 = accT, a2 = redge;
    #pragma unroll
    for (int off = 32; off; off >>= 1) {
      a0 += __shfl_down(a0, off, 64);
      a1 += __shfl_down(a1, off, 64);
      a2 += __shfl_down(a2, off, 64);
    }
    if (lane == 0) { red[wid] = a0; red[4 + wid] = a1; red[8 + wid] = a2; }
    __syncthreads();
    if (tid == 0) {   // single writer per block (release-fence friendly)
      float* pp = predpart + pb * 8;
      pp[0] = (red[0] + red[1]) + (red[2] + red[3]);
      pp[1] = (red[4] + red[5]) + (red[6] + red[7]);
      pp[4] = (red[8] + red[9]) + (red[10] + red[11]);
      pp[2] = accC; pp[5] = cornA;
      pp[3] = s_edge[0]; pp[6] = s_edge[1];
    }
  }

  // ---------------- ticket: last of the 72 producers runs batch b's tail ----
  __shared__ int s_do_tail;
  __syncthreads();
  if (tid == 0) {
    __threadfence();   // release all this block's global writes (tid0 wrote them)
    const int old = __hip_atomic_fetch_add(&cnt[b], 1, __ATOMIC_ACQ_REL,
                                           __HIP_MEMORY_SCOPE_AGENT);
    s_do_tail = (old == 71) ? 1 : 0;
  }
  __syncthreads();
  if (!s_do_tail) return;

  // ---------------- tail for batch b (256 threads; waves 0-1 compute) -------
  const int t = tid, ln = t & 63;
  __shared__ float a[64], hd[64], pf[128], hf[128], gate[64];
  __shared__ float hgate[64], pgate[64], pfo[64], hfo[64], upd[64];
  __shared__ float s_pp[64];
  __shared__ float s_sP;

  float sf = 0.f;
  if (t < 64) {
    sf      = aload(&sumF[b * 64 + t]);       // agent-scope: cross-XCD safe
    s_pp[t] = aload(&predpart[b * 64 + t]);
    hd[t]   = head[b * 64 + t];
  }
  __syncthreads();

  if (t == 0) {
    float P = 0.f, T = 0.f, C0 = 0.f, C255 = 0.f;
    #pragma unroll
    for (int g = 0; g < 8; ++g) {
      P += s_pp[g*8 + 0]; T += s_pp[g*8 + 1]; C0 += s_pp[g*8 + 2]; C255 += s_pp[g*8 + 3];
    }
    const float R0 = s_pp[0*8 + 4], R255 = s_pp[7*8 + 4];
    const float k00 = s_pp[0*8 + 5], k01 = s_pp[0*8 + 6];
    const float k10 = s_pp[7*8 + 5], k11 = s_pp[7*8 + 6];
    auto rect = [&](int du, int dv) -> float {
      float r = T;
      if (du > 0) r -= R0; else if (du < 0) r -= R255;
      if (dv > 0) r -= C0; else if (dv < 0) r -= C255;
      if (du > 0 && dv > 0) r += k00;
      else if (du > 0 && dv < 0) r += k01;
      else if (du < 0 && dv > 0) r += k10;
      else if (du < 0 && dv < 0) r += k11;
      return r;
    };
    float S = P + 65536.f * dw_b[0];
    #pragma unroll
    for (int u = 0; u < 3; ++u)
      #pragma unroll
      for (int v = 0; v < 3; ++v)
        S += dw_w[u*3+v] * rect(u-1, v-1);
    s_sP = S;
  }
  __syncthreads();
  if (t < 64) a[t] = sf * s_sP;
  __syncthreads();

  if (t < 128) { // pred_feat / head_feat linears (128 outputs each)
    const float4* ptw4 = reinterpret_cast<const float4*>(pt_w) + t * 16;
    const float4* htw4 = reinterpret_cast<const float4*>(ht_w) + t * 16;
    const float4* a4  = reinterpret_cast<const float4*>(a);
    const float4* hd4 = reinterpret_cast<const float4*>(hd);
    float sp = pt_b[t], sh = ht_b[t];
    #pragma unroll
    for (int kk = 0; kk < 16; ++kk) {
      const float4 wp = ptw4[kk], wh = htw4[kk];
      const float4 av = a4[kk],  hv = hd4[kk];
      sp += av.x*wp.x + av.y*wp.y + av.z*wp.z + av.w*wp.w;
      sh += hv.x*wh.x + hv.y*wh.y + hv.z*wh.z + hv.w*wh.w;
    }
    pf[t] = sp; hf[t] = sh;
  }
  __syncthreads();
  if (t < 64) gate[t] = hf[t] * pf[t];
  __syncthreads();

  if (t < 128) {
    float glin;
    {
      const float* gw = (t < 64) ? hg_w : pg_w;
      float s = (t < 64) ? hg_b[ln] : pg_b[ln];
      const float4* gw4 = reinterpret_cast<const float4*>(gw) + ln * 16;
      const float4* g4  = reinterpret_cast<const float4*>(gate);
      #pragma unroll
      for (int kk = 0; kk < 16; ++kk) {
        const float4 w = gw4[kk], gv = g4[kk];
        s += gv.x*w.x + gv.y*w.y + gv.z*w.z + gv.w*w.w;
      }
      glin = s;
    }
    { // LN + sigmoid per wave
      const float m = wsum64(glin) * (1.f/64.f);
      const float d = glin - m;
      const float var = wsum64(d*d) * (1.f/64.f);
      const float* gg = (t < 64) ? hni_g : pni_g;
      const float* bb = (t < 64) ? hni_b : pni_b;
      const float y = d / sqrtf(var + 1e-5f) * gg[ln] + bb[ln];
      const float sg = 1.f / (1.f + expf(-y));
      if (t < 64) hgate[ln] = sg; else pgate[ln] = sg;
    }
    { // LN of the out-halves
      const float x = (t < 64) ? hf[64 + ln] : pf[64 + ln];
      const float m = wsum64(x) * (1.f/64.f);
      const float d = x - m;
      const float var = wsum64(d*d) * (1.f/64.f);
      const float* gg = (t < 64) ? hno_g : pno_g;
      const float* bb = (t < 64) ? hno_b : pno_b;
      const float y = d / sqrtf(var + 1e-5f) * gg[ln] + bb[ln];
      if (t < 64) hfo[ln] = y; else pfo[ln] = y;
    }
  }
  __syncthreads();
  if (t < 64) upd[t] = pgate[t] * pfo[t] + hgate[t] * hfo[t];
  __syncthreads();
  if (t < 64) {
    const float4* fw4 = reinterpret_cast<const float4*>(fc_w) + t * 16;
    const float4* u4  = reinterpret_cast<const float4*>(upd);
    float s = fc_b[t];
    #pragma unroll
    for (int kk = 0; kk < 16; ++kk) {
      const float4 w = fw4[kk], uv = u4[kk];
      s += uv.x*w.x + uv.y*w.y + uv.z*w.z + uv.w*w.w;
    }
    const float m = wsum64(s) * (1.f/64.f);
    const float d = s - m;
    const float var = wsum64(d*d) * (1.f/64.f);
    const float y = d / sqrtf(var + 1e-5f) * fcn_g[t] + fcn_b[t];
    out[b * 64 + t] = fmaxf(y, 0.f);
  }
}

// ---------------------------------------------------------------------------
extern "C" void kernel_launch(void* const* d_in, const int* in_sizes, int n_in,
                              void* d_out, int out_size, void* d_ws, size_t ws_size,
                              hipStream_t stream) {
  (void)in_sizes; (void)n_in; (void)out_size; (void)ws_size;
  const float* feat     = (const float*)d_in[0];
  const float* head     = (const float*)d_in[1];
  const float* pred     = (const float*)d_in[2];
  const float* dw_w     = (const float*)d_in[3];
  const float* dw_b     = (const float*)d_in[4];
  const float* inc_hw_w = (const float*)d_in[5];
  const float* inc_hw_b = (const float*)d_in[6];
  const float* inc_w_w  = (const float*)d_in[7];
  const float* inc_w_b  = (const float*)d_in[8];
  const float* inc_h_w  = (const float*)d_in[9];
  const float* inc_h_b  = (const float*)d_in[10];
  const float* pt_w  = (const float*)d_in[11];
  const float* pt_b  = (const float*)d_in[12];
  const float* ht_w  = (const float*)d_in[13];
  const float* ht_b  = (const float*)d_in[14];
  const float* pg_w  = (const float*)d_in[15];
  const float* pg_b  = (const float*)d_in[16];
  const float* hg_w  = (const float*)d_in[17];
  const float* hg_b  = (const float*)d_in[18];
  const float* fc_w  = (const float*)d_in[19];
  const float* fc_b  = (const float*)d_in[20];
  const float* pni_g = (const float*)d_in[21];
  const float* pni_b = (const float*)d_in[22];
  const float* hni_g = (const float*)d_in[23];
  const float* hni_b = (const float*)d_in[24];
  const float* pno_g = (const float*)d_in[25];
  const float* pno_b = (const float*)d_in[26];
  const float* hno_g = (const float*)d_in[27];
  const float* hno_b = (const float*)d_in[28];
  const float* fcn_g = (const float*)d_in[29];
  const float* fcn_b = (const float*)d_in[30];

  float* out      = (float*)d_out;
  float* sumF     = (float*)d_ws;                    // 1024 floats
  float* predpart = sumF + 1024;                     // 1024 floats
  int*   cnt      = (int*)((char*)d_ws + 8192);      // 16 ints

  hipMemsetAsync(cnt, 0, 16 * sizeof(int), stream);  // graph-safe tiny fill

  k_all<<<1152, 256, 0, stream>>>(feat, pred,
                                  inc_hw_w, inc_hw_b, inc_w_w, inc_w_b,
                                  inc_h_w, inc_h_b,
                                  head, dw_w, dw_b,
                                  pt_w, pt_b, ht_w, ht_b,
                                  pg_w, pg_b, hg_w, hg_b, fc_w, fc_b,
                                  pni_g, pni_b, hni_g, hni_b,
                                  pno_g, pno_b, hno_g, hno_b,
                                  fcn_g, fcn_b,
                                  sumF, predpart, cnt, out);
}

// Round 6
// 52.211 us; speedup vs baseline: 2.9000x; 2.9000x over previous
//
#include <hip/hip_runtime.h>
#include <math.h>

// ws layout: sumF4[1024][4] f32 (16 KB) | predpart[16*8*8] f32 at +16384
//
// Identities (verified exact, absmax 0.0 in rounds 1-4):
//  - sum(irfft2(rfft2(p)*rfft2(f))) over space = sum(p)*sum(f)   (circular conv)
//  - spatial sum of zero-padded depthwise conv = sum_w w[u,v]*RectSum + N*bias,
//    RectSum needs only plane total + <=5-wide border row/col sums (+corners).
// Round-5 lesson: per-block device-scope fences serialize at the per-XCD L2s
// and destroy streaming BW -> NO single-kernel fusion; plain 2-kernel graph.
// Round-6 change: identity planes split into quarter-plane blocks (finer
// end-of-grid packing); conv planes stay whole (border capture needs the
// full plane in one block).

typedef float nfloat4 __attribute__((ext_vector_type(4)));

// grid layout: [0,128)   pred partial blocks (16 batches x 8 row groups)
//              [128,512) conv planes, whole (384 = 16 batches x 24 planes)
//              [512,3072) identity quarter-planes (640 planes x 4)
__global__ __launch_bounds__(256) void k_main(
    const float* __restrict__ feat,
    const float* __restrict__ pred,
    const float* __restrict__ w_hw, const float* __restrict__ b_hw,
    const float* __restrict__ w_w,  const float* __restrict__ b_w,
    const float* __restrict__ w_h,  const float* __restrict__ b_h,
    float* __restrict__ sumF4,       // [1024][4]
    float* __restrict__ predpart)    // [16][8][8]
{
  const int tid  = threadIdx.x;
  const int lane = tid & 63;
  const int wid  = tid >> 6;

  if (blockIdx.x >= 512) {
    // ---- identity quarter-plane: pure branch-free sum of 64 rows
    const int qb    = blockIdx.x - 512;        // 0..2559
    const int pidx  = qb >> 2;                 // 0..639 (b*40 + c)
    const int q     = qb & 3;
    const int b     = pidx / 40;
    const int c     = pidx % 40;
    const int plane = b * 64 + c;
    const nfloat4* x4 = reinterpret_cast<const nfloat4*>(feat)
                      + (size_t)plane * 16384 + q * 4096;
    __shared__ float red_i[4];
    float ax = 0.f, ay = 0.f, az = 0.f, aw = 0.f;
    #pragma unroll 8
    for (int it = 0; it < 16; ++it) {
      const nfloat4 v = __builtin_nontemporal_load(&x4[it * 256 + tid]);
      ax += v.x; ay += v.y; az += v.z; aw += v.w;
    }
    float tot = (ax + ay) + (az + aw);
    #pragma unroll
    for (int off = 32; off; off >>= 1) tot += __shfl_down(tot, off, 64);
    if (lane == 0) red_i[wid] = tot;
    __syncthreads();
    if (tid == 0)
      sumF4[plane * 4 + q] = (red_i[0] + red_i[1]) + (red_i[2] + red_i[3]);
    return;
  }

  if (blockIdx.x >= 128) {
    // ---- conv plane (whole): sum + inline border captures
    const int cp    = blockIdx.x - 128;        // 0..383
    const int b     = cp / 24;
    const int c     = 40 + cp % 24;
    const int plane = b * 64 + c;
    const nfloat4* x4 = reinterpret_cast<const nfloat4*>(feat) + (size_t)plane * 16384;

    __shared__ float s_red[4];
    __shared__ float s_rs[10];        // rows 0..4 -> 0..4, rows 251..255 -> 5..9
    __shared__ float s_cs4[4][10];    // per-wave col partials, same index map
    __shared__ float s_k[4];          // corners (0,0),(0,255),(255,0),(255,255)

    float ax = 0.f, ay = 0.f, az = 0.f, aw = 0.f;
    float rowA = 0.f, rowB = 0.f, rowC = 0.f, rowD = 0.f;
    float v0x = 0.f, v0w = 0.f, v63x = 0.f, v63w = 0.f;
    #pragma unroll 8
    for (int it = 0; it < 64; ++it) {
      const nfloat4 v = __builtin_nontemporal_load(&x4[it * 256 + tid]);
      ax += v.x; ay += v.y; az += v.z; aw += v.w;
      const float s4 = (v.x + v.y) + (v.z + v.w);
      rowA += (it == 0)  ? s4 : 0.f;     // row = wid
      rowB += (it == 1)  ? s4 : 0.f;     // row = 4 + wid
      rowC += (it == 62) ? s4 : 0.f;     // row = 248 + wid
      rowD += (it == 63) ? s4 : 0.f;     // row = 252 + wid
      if (it == 0)  { v0x = v.x;  v0w = v.w; }
      if (it == 63) { v63x = v.x; v63w = v.w; }
    }
    float tot = (ax + ay) + (az + aw);
    float r0 = rowA, r1 = rowB, r2 = rowC, r3 = rowD;
    #pragma unroll
    for (int off = 32; off; off >>= 1) {
      tot += __shfl_down(tot, off, 64);
      r0  += __shfl_down(r0, off, 64);
      r1  += __shfl_down(r1, off, 64);
      r2  += __shfl_down(r2, off, 64);
      r3  += __shfl_down(r3, off, 64);
    }
    if (lane == 0) {
      s_red[wid] = tot;
      s_rs[wid] = r0;                     // rows 0..3
      if (wid == 0) s_rs[4] = r1;         // row 4
      if (wid == 3) s_rs[5] = r2;         // row 251
      s_rs[6 + wid] = r3;                 // rows 252..255
      s_cs4[wid][0] = ax; s_cs4[wid][1] = ay; s_cs4[wid][2] = az; s_cs4[wid][3] = aw;
    }
    if (lane == 1)  { s_cs4[wid][4] = ax; }                // col 4
    if (lane == 62) { s_cs4[wid][5] = aw; }                // col 251
    if (lane == 63) { s_cs4[wid][6] = ax; s_cs4[wid][7] = ay;
                      s_cs4[wid][8] = az; s_cs4[wid][9] = aw; }  // cols 252..255
    if (tid == 0)   s_k[0] = v0x;      // row 0,   col 0
    if (tid == 63)  s_k[1] = v0w;      // row 0,   col 255
    if (tid == 192) s_k[2] = v63x;     // row 255, col 0
    if (tid == 255) s_k[3] = v63w;     // row 255, col 255
    __syncthreads();

    if (tid == 0) {
      const float T = (s_red[0] + s_red[1]) + (s_red[2] + s_red[3]);
      float cs[10];
      #pragma unroll
      for (int k = 0; k < 10; ++k)
        cs[k] = (s_cs4[0][k] + s_cs4[1][k]) + (s_cs4[2][k] + s_cs4[3][k]);
      const float k00 = s_k[0], k01 = s_k[1], k10 = s_k[2], k11 = s_k[3];

      float topP[6], botP[6], leftP[6], rightP[6];
      topP[0] = botP[0] = leftP[0] = rightP[0] = 0.f;
      #pragma unroll
      for (int k = 0; k < 5; ++k) {
        topP[k+1]   = topP[k]   + s_rs[k];
        botP[k+1]   = botP[k]   + s_rs[9-k];
        leftP[k+1]  = leftP[k]  + cs[k];
        rightP[k+1] = rightP[k] + cs[9-k];
      }
      auto rect = [&](int du, int dv) -> float {
        float r = T;
        if (du > 0) r -= topP[du]; else if (du < 0) r -= botP[-du];
        if (dv > 0) r -= leftP[dv]; else if (dv < 0) r -= rightP[-dv];
        if (du > 0 && dv > 0) r += k00;
        else if (du > 0 && dv < 0) r += k01;
        else if (du < 0 && dv > 0) r += k10;
        else if (du < 0 && dv < 0) r += k11;
        return r;
      };
      float S;
      if (c < 48) {                       // 3x3 depthwise, pad (1,1)
        const int g = c - 40; const float* w = w_hw + g * 9;
        S = 65536.f * b_hw[g];
        #pragma unroll
        for (int u = 0; u < 3; ++u)
          #pragma unroll
          for (int v = 0; v < 3; ++v)
            S += w[u*3+v] * rect(u-1, v-1);
      } else if (c < 56) {                // 1x11 depthwise, pad (0,5)
        const int g = c - 48; const float* w = w_w + g * 11;
        S = 65536.f * b_w[g];
        #pragma unroll
        for (int v = 0; v < 11; ++v) S += w[v] * rect(0, v-5);
      } else {                            // 11x1 depthwise, pad (5,0)
        const int g = c - 56; const float* w = w_h + g * 11;
        S = 65536.f * b_h[g];
        #pragma unroll
        for (int u = 0; u < 11; ++u) S += w[u] * rect(u-5, 0);
      }
      sumF4[plane * 4] = S;               // slot 0 only (tail reads slot 0 for conv)
    }
    return;
  }

  // ---- pred partial: block pb handles output rows [g*32, g*32+32)
  __shared__ float red[12];
  const int pb = blockIdx.x;
  const int b  = pb >> 3;
  const int g  = pb & 7;
  const int j  = tid;                 // output column 0..255
  const float* src = pred + (size_t)b * 16384;

  // jax bilinear 2x (half-pixel, edge clamp): even .25/.75, odd .75/.25
  const int kj = j >> 1;
  int c0, c1; float wc0, wc1;
  if ((j & 1) == 0) { c0 = (kj > 0) ? kj - 1 : 0; c1 = kj; wc0 = 0.25f; wc1 = 0.75f; }
  else              { c0 = kj; c1 = (kj < 127) ? kj + 1 : 127; wc0 = 0.75f; wc1 = 0.25f; }

  float accP = 0.f, accT = 0.f, accC = 0.f, redge = 0.f, cornA = 0.f, cornB = 0.f;
  const int i0 = g * 32;
  #pragma unroll 4
  for (int i = i0; i < i0 + 32; ++i) {
    const int ki = i >> 1;
    int r0, r1; float wr0, wr1;
    if ((i & 1) == 0) { r0 = (ki > 0) ? ki - 1 : 0; r1 = ki; wr0 = 0.25f; wr1 = 0.75f; }
    else              { r0 = ki; r1 = (ki < 127) ? ki + 1 : 127; wr0 = 0.75f; wr1 = 0.25f; }
    const float v = wr0 * (wc0 * src[r0*128 + c0] + wc1 * src[r0*128 + c1])
                  + wr1 * (wc0 * src[r1*128 + c0] + wc1 * src[r1*128 + c1]);
    const float p  = 1.f / (1.f + expf(-v));
    const float pm = 1.f - 1.f / (1.f + expf(-p));
    const float pa = p * pm + p;
    accP += p; accT += pa;
    if (j == 0 || j == 255) accC += pa;
    if (i == 0 || i == 255) {         // only reachable in g==0 / g==7
      redge += pa;
      if (j == 0)   cornA = pa;
      if (j == 255) cornB = pa;
    }
  }
  float a0 = accP, a1 = accT, a2 = redge;
  #pragma unroll
  for (int off = 32; off; off >>= 1) {
    a0 += __shfl_down(a0, off, 64);
    a1 += __shfl_down(a1, off, 64);
    a2 += __shfl_down(a2, off, 64);
  }
  if (lane == 0) { red[wid] = a0; red[4 + wid] = a1; red[8 + wid] = a2; }
  __syncthreads();
  float* pp = predpart + pb * 8;
  if (tid == 0) {
    pp[0] = (red[0] + red[1]) + (red[2] + red[3]);
    pp[1] = (red[4] + red[5]) + (red[6] + red[7]);
    pp[4] = (red[8] + red[9]) + (red[10] + red[11]);
    pp[2] = accC; pp[5] = cornA;
  }
  if (tid == 255) { pp[3] = accC; pp[6] = cornB; }
}

// ---------------------------------------------------------------------------
// Kernel B: combine partials -> sumP/sumF, then the MLP/LN/gate tail.
// One block per batch, 128 threads (2 waves).
// ---------------------------------------------------------------------------
__device__ __forceinline__ float wsum64(float v) {
  #pragma unroll
  for (int off = 32; off; off >>= 1) v += __shfl_xor(v, off, 64);
  return v;
}

__global__ __launch_bounds__(128) void k_tail(
    const float* __restrict__ sumF4, const float* __restrict__ predpart,
    const float* __restrict__ head,
    const float* __restrict__ dw_w, const float* __restrict__ dw_b,
    const float* __restrict__ pt_w, const float* __restrict__ pt_b,
    const float* __restrict__ ht_w, const float* __restrict__ ht_b,
    const float* __restrict__ pg_w, const float* __restrict__ pg_b,
    const float* __restrict__ hg_w, const float* __restrict__ hg_b,
    const float* __restrict__ fc_w, const float* __restrict__ fc_b,
    const float* __restrict__ pni_g, const float* __restrict__ pni_b,
    const float* __restrict__ hni_g, const float* __restrict__ hni_b,
    const float* __restrict__ pno_g, const float* __restrict__ pno_b,
    const float* __restrict__ hno_g, const float* __restrict__ hno_b,
    const float* __restrict__ fcn_g, const float* __restrict__ fcn_b,
    float* __restrict__ out)
{
  const int b = blockIdx.x;
  const int t = threadIdx.x;      // 0..127
  const int ln = t & 63;
  __shared__ float a[64], hd[64], pf[128], hf[128], gate[64];
  __shared__ float hgate[64], pgate[64], pfo[64], hfo[64], upd[64];
  __shared__ float s_sP;

  float sf = 0.f;
  if (t < 64) {
    const float4 qv = *reinterpret_cast<const float4*>(&sumF4[(b * 64 + t) * 4]);
    sf = (t < 40) ? ((qv.x + qv.y) + (qv.z + qv.w)) : qv.x;
    hd[t] = head[b * 64 + t];
  }

  if (t == 0) {
    const float* pp = predpart + b * 64;   // [8][8], fixed combine order
    float P = 0.f, T = 0.f, C0 = 0.f, C255 = 0.f;
    #pragma unroll
    for (int g = 0; g < 8; ++g) {
      P += pp[g*8 + 0]; T += pp[g*8 + 1]; C0 += pp[g*8 + 2]; C255 += pp[g*8 + 3];
    }
    const float R0 = pp[0*8 + 4], R255 = pp[7*8 + 4];
    const float k00 = pp[0*8 + 5], k01 = pp[0*8 + 6];
    const float k10 = pp[7*8 + 5], k11 = pp[7*8 + 6];
    auto rect = [&](int du, int dv) -> float {
      float r = T;
      if (du > 0) r -= R0; else if (du < 0) r -= R255;
      if (dv > 0) r -= C0; else if (dv < 0) r -= C255;
      if (du > 0 && dv > 0) r += k00;
      else if (du > 0 && dv < 0) r += k01;
      else if (du < 0 && dv > 0) r += k10;
      else if (du < 0 && dv < 0) r += k11;
      return r;
    };
    float S = P + 65536.f * dw_b[0];
    #pragma unroll
    for (int u = 0; u < 3; ++u)
      #pragma unroll
      for (int v = 0; v < 3; ++v)
        S += dw_w[u*3+v] * rect(u-1, v-1);
    s_sP = S;
  }
  __syncthreads();
  if (t < 64) a[t] = sf * s_sP;
  __syncthreads();

  { // pred_feat / head_feat linears (128 outputs each), float4 weight rows
    const float4* ptw4 = reinterpret_cast<const float4*>(pt_w) + t * 16;
    const float4* htw4 = reinterpret_cast<const float4*>(ht_w) + t * 16;
    const float4* a4  = reinterpret_cast<const float4*>(a);
    const float4* hd4 = reinterpret_cast<const float4*>(hd);
    float sp = pt_b[t], sh = ht_b[t];
    #pragma unroll
    for (int kk = 0; kk < 16; ++kk) {
      const float4 wp = ptw4[kk], wh = htw4[kk];
      const float4 av = a4[kk],  hv = hd4[kk];
      sp += av.x*wp.x + av.y*wp.y + av.z*wp.z + av.w*wp.w;
      sh += hv.x*wh.x + hv.y*wh.y + hv.z*wh.z + hv.w*wh.w;
    }
    pf[t] = sp; hf[t] = sh;
  }
  __syncthreads();
  if (t < 64) gate[t] = hf[t] * pf[t];
  __syncthreads();

  float glin;
  {
    const float* gw = (t < 64) ? hg_w : pg_w;
    float s = (t < 64) ? hg_b[ln] : pg_b[ln];
    const float4* gw4 = reinterpret_cast<const float4*>(gw) + ln * 16;
    const float4* g4  = reinterpret_cast<const float4*>(gate);
    #pragma unroll
    for (int kk = 0; kk < 16; ++kk) {
      const float4 w = gw4[kk], gv = g4[kk];
      s += gv.x*w.x + gv.y*w.y + gv.z*w.z + gv.w*w.w;
    }
    glin = s;
  }
  { // LN + sigmoid per wave
    const float m = wsum64(glin) * (1.f/64.f);
    const float d = glin - m;
    const float var = wsum64(d*d) * (1.f/64.f);
    const float* g  = (t < 64) ? hni_g : pni_g;
    const float* bb = (t < 64) ? hni_b : pni_b;
    const float y = d / sqrtf(var + 1e-5f) * g[ln] + bb[ln];
    const float sg = 1.f / (1.f + expf(-y));
    if (t < 64) hgate[ln] = sg; else pgate[ln] = sg;
  }
  { // LN of the out-halves
    const float x = (t < 64) ? hf[64 + ln] : pf[64 + ln];
    const float m = wsum64(x) * (1.f/64.f);
    const float d = x - m;
    const float var = wsum64(d*d) * (1.f/64.f);
    const float* g  = (t < 64) ? hno_g : pno_g;
    const float* bb = (t < 64) ? hno_b : pno_b;
    const float y = d / sqrtf(var + 1e-5f) * g[ln] + bb[ln];
    if (t < 64) hfo[ln] = y; else pfo[ln] = y;
  }
  __syncthreads();
  if (t < 64) upd[t] = pgate[t] * pfo[t] + hgate[t] * hfo[t];
  __syncthreads();
  if (t < 64) {
    const float4* fw4 = reinterpret_cast<const float4*>(fc_w) + t * 16;
    const float4* u4  = reinterpret_cast<const float4*>(upd);
    float s = fc_b[t];
    #pragma unroll
    for (int kk = 0; kk < 16; ++kk) {
      const float4 w = fw4[kk], uv = u4[kk];
      s += uv.x*w.x + uv.y*w.y + uv.z*w.z + uv.w*w.w;
    }
    const float m = wsum64(s) * (1.f/64.f);
    const float d = s - m;
    const float var = wsum64(d*d) * (1.f/64.f);
    const float y = d / sqrtf(var + 1e-5f) * fcn_g[t] + fcn_b[t];
    out[b * 64 + t] = fmaxf(y, 0.f);
  }
}

// ---------------------------------------------------------------------------
extern "C" void kernel_launch(void* const* d_in, const int* in_sizes, int n_in,
                              void* d_out, int out_size, void* d_ws, size_t ws_size,
                              hipStream_t stream) {
  (void)in_sizes; (void)n_in; (void)out_size; (void)ws_size;
  const float* feat     = (const float*)d_in[0];
  const float* head     = (const float*)d_in[1];
  const float* pred     = (const float*)d_in[2];
  const float* dw_w     = (const float*)d_in[3];
  const float* dw_b     = (const float*)d_in[4];
  const float* inc_hw_w = (const float*)d_in[5];
  const float* inc_hw_b = (const float*)d_in[6];
  const float* inc_w_w  = (const float*)d_in[7];
  const float* inc_w_b  = (const float*)d_in[8];
  const float* inc_h_w  = (const float*)d_in[9];
  const float* inc_h_b  = (const float*)d_in[10];
  const float* pt_w  = (const float*)d_in[11];
  const float* pt_b  = (const float*)d_in[12];
  const float* ht_w  = (const float*)d_in[13];
  const float* ht_b  = (const float*)d_in[14];
  const float* pg_w  = (const float*)d_in[15];
  const float* pg_b  = (const float*)d_in[16];
  const float* hg_w  = (const float*)d_in[17];
  const float* hg_b  = (const float*)d_in[18];
  const float* fc_w  = (const float*)d_in[19];
  const float* fc_b  = (const float*)d_in[20];
  const float* pni_g = (const float*)d_in[21];
  const float* pni_b = (const float*)d_in[22];
  const float* hni_g = (const float*)d_in[23];
  const float* hni_b = (const float*)d_in[24];
  const float* pno_g = (const float*)d_in[25];
  const float* pno_b = (const float*)d_in[26];
  const float* hno_g = (const float*)d_in[27];
  const float* hno_b = (const float*)d_in[28];
  const float* fcn_g = (const float*)d_in[29];
  const float* fcn_b = (const float*)d_in[30];

  float* out      = (float*)d_out;
  float* sumF4    = (float*)d_ws;                    // 4096 floats (16 KB)
  float* predpart = (float*)((char*)d_ws + 16384);   // 1024 floats

  k_main<<<3072, 256, 0, stream>>>(feat, pred,
                                   inc_hw_w, inc_hw_b, inc_w_w, inc_w_b,
                                   inc_h_w, inc_h_b, sumF4, predpart);
  k_tail<<<16, 128, 0, stream>>>(sumF4, predpart, head, dw_w, dw_b,
                                 pt_w, pt_b, ht_w, ht_b,
                                 pg_w, pg_b, hg_w, hg_b, fc_w, fc_b,
                                 pni_g, pni_b, hni_g, hni_b,
                                 pno_g, pno_b, hno_g, hno_b,
                                 fcn_g, fcn_b, out);
}